// Round 4
// baseline (332.873 us; speedup 1.0000x reference)
//
#include <hip/hip_runtime.h>

// Fused DigitConvolutionalModel, R4:
//   conv3x3(valid) 28x28 -> 676 -> fc1(100)+ReLU (bf16 MFMA 16x16x32) -> fc2(10)
// BM=32 images/block, 256 thr (4 waves). Each wave: 2 m-tiles x 2 n-tiles,
// so each B-fragment load feeds 2 MFMAs (B L2 traffic halves vs R3: 360 MB).
// Conv uses full-row tasks with compile-time indexing only (R3's runtime
// rowv[c+dc+h] caused select-chain VALU bloat). launch_bounds(256,4): VGPR
// cap 128 (R2's cap-85 spill disaster avoided). LDS 45.6 KB -> 3 blocks/CU.

typedef short  s16x8 __attribute__((ext_vector_type(8)));   // 8 bf16
typedef float  f32x4 __attribute__((ext_vector_type(4)));   // 16x16 acc

#define BM   32     // images per block
#define CSTR 712    // cbuf row stride in bf16 (1424 B; dword stride 356 = 4 mod 32 -> 2-way = free)
#define HSTR 132    // hbuf row stride in floats (cols 0..127 written)
#define NT   8      // n-tiles of 16 (N=100 -> 7 live + 1 zero tile)
#define KC   22     // k-chunks of 32 (K=676 -> pad 704, bias row at k=676)

__device__ __forceinline__ unsigned short f2bf(float f) {
    unsigned int u = __builtin_bit_cast(unsigned int, f);
    u = (u + 0x7fffu + ((u >> 16) & 1u)) >> 16;
    return (unsigned short)u;
}

// ---- prep: W1 [100][676] fp32 -> bw [t][kc][lane][8] bf16 (B-fragment) ----
// lane (n=lane&15, q=lane>>4) holds B[k = kc*32 + q*8 + j][n = t*16 + (lane&15)]
// k==676 -> b1[n] (bias row); n>=100 or k>676 -> 0.
extern "C" __global__ void __launch_bounds__(256)
prep_w1(const float* __restrict__ W1, const float* __restrict__ b1,
        unsigned short* __restrict__ bw)
{
    int id = blockIdx.x * 256 + threadIdx.x;
    if (id >= NT * KC * 64) return;
    int lane = id & 63;
    int kc   = (id >> 6) % KC;
    int t    = id / (KC * 64);
    int n    = t * 16 + (lane & 15);
    int k0   = kc * 32 + (lane >> 4) * 8;
    unsigned short v[8];
#pragma unroll
    for (int j = 0; j < 8; ++j) {
        int k = k0 + j;
        float f = 0.f;
        if (n < 100) {
            if (k < 676)       f = W1[(size_t)n * 676 + k];
            else if (k == 676) f = b1[n];
        }
        v[j] = f2bf(f);
    }
    *(uint4*)(bw + (size_t)id * 8) = *(const uint4*)v;
}

// ---------------------------- main kernel ----------------------------------
extern "C" __global__ void __launch_bounds__(256, 4)
digit_model_fused(const float* __restrict__ x,
                  const float* __restrict__ cw9,
                  const unsigned short* __restrict__ bw,
                  const float* __restrict__ W2,
                  const float* __restrict__ b2,
                  float* __restrict__ out)
{
    __shared__ __align__(16) unsigned char smem[BM * CSTR * 2]; // 45568 B
    unsigned short* cbuf = (unsigned short*)smem;   // phase 1/2: bf16 A-tile
    float*          hbuf = (float*)smem;            // phase 3: fp32 h (aliased)

    const int tid  = threadIdx.x;
    const int lane = tid & 63;
    const int wv   = tid >> 6;       // 0..3
    const int q    = lane >> 4;      // k-quarter
    const int mn   = lane & 15;      // m within tile (A rows / C rows) & n col
    const int m0   = blockIdx.x * BM;

    float cw[9];
#pragma unroll
    for (int i = 0; i < 9; ++i) cw[i] = cw9[i];

    // K-pad [676,712): zeros except A[mi][676] = 1.0 (bias multiplicand)
    for (int p = tid; p < BM * 18; p += 256) {
        int mi = p / 18, qq = p - mi * 18;
        *(unsigned int*)(cbuf + mi * CSTR + 676 + qq * 2) = (qq == 0) ? 0x3F80u : 0u;
    }

    // -------- Phase 1: conv fp32, full-row tasks (26 outputs) ---------------
    for (int task = tid; task < BM * 26; task += 256) {
        int mi = task / 26, r = task - mi * 26;
        const float* ip = x + (size_t)(m0 + mi) * 784 + r * 28;
        float acc[26];
#pragma unroll
        for (int c = 0; c < 26; ++c) acc[c] = 0.f;
#pragma unroll
        for (int dr = 0; dr < 3; ++dr) {
            float rowv[28];
            const float4* rp = (const float4*)(ip + dr * 28);   // 16B aligned
#pragma unroll
            for (int g = 0; g < 7; ++g) {
                float4 v = rp[g];
                rowv[g*4+0] = v.x; rowv[g*4+1] = v.y;
                rowv[g*4+2] = v.z; rowv[g*4+3] = v.w;
            }
#pragma unroll
            for (int dc = 0; dc < 3; ++dc) {
                float w = cw[dr*3+dc];
#pragma unroll
                for (int c = 0; c < 26; ++c)
                    acc[c] = fmaf(rowv[c + dc], w, acc[c]);   // all idx compile-time
            }
        }
        unsigned short* dst = cbuf + mi * CSTR + r * 26;   // 4B aligned
#pragma unroll
        for (int c = 0; c < 26; c += 2)
            *(unsigned int*)(dst + c) =
                (unsigned int)f2bf(acc[c]) | ((unsigned int)f2bf(acc[c+1]) << 16);
    }
    __syncthreads();

    // -------- Phase 2: MFMA 16x16x32, 2 m-tiles x 2 n-tiles per wave --------
    // A: lane holds A[m=mn][k=q*8+j]; B: lane holds B[k=q*8+j][n=mn]
    f32x4 acc00, acc01, acc10, acc11;   // [mtile][ntile]
#pragma unroll
    for (int i = 0; i < 4; ++i) { acc00[i]=0.f; acc01[i]=0.f; acc10[i]=0.f; acc11[i]=0.f; }

    const unsigned short* arow0 = cbuf + mn * CSTR + q * 8;          // images 0-15
    const unsigned short* arow1 = cbuf + (16 + mn) * CSTR + q * 8;   // images 16-31
    const uint4* bwv = (const uint4*)bw;
    const int t0 = wv, t1 = wv + 4;

    uint4 a0 = *(const uint4*)(arow0);               // ds_read_b128
    uint4 a1 = *(const uint4*)(arow1);
    uint4 b0 = bwv[(t0 * KC) * 64 + lane];           // coalesced 1KB/wave
    uint4 b1 = bwv[(t1 * KC) * 64 + lane];
    for (int kc = 0; kc < KC; ++kc) {
        int kn = (kc + 1 < KC) ? kc + 1 : kc;        // clamped 1-deep prefetch
        uint4 na0 = *(const uint4*)(arow0 + kn * 32);
        uint4 na1 = *(const uint4*)(arow1 + kn * 32);
        uint4 nb0 = bwv[(t0 * KC + kn) * 64 + lane];
        uint4 nb1 = bwv[(t1 * KC + kn) * 64 + lane];
        s16x8 av0 = __builtin_bit_cast(s16x8, a0), av1 = __builtin_bit_cast(s16x8, a1);
        s16x8 bv0 = __builtin_bit_cast(s16x8, b0), bv1 = __builtin_bit_cast(s16x8, b1);
        acc00 = __builtin_amdgcn_mfma_f32_16x16x32_bf16(av0, bv0, acc00, 0, 0, 0);
        acc01 = __builtin_amdgcn_mfma_f32_16x16x32_bf16(av0, bv1, acc01, 0, 0, 0);
        acc10 = __builtin_amdgcn_mfma_f32_16x16x32_bf16(av1, bv0, acc10, 0, 0, 0);
        acc11 = __builtin_amdgcn_mfma_f32_16x16x32_bf16(av1, bv1, acc11, 0, 0, 0);
        a0 = na0; a1 = na1; b0 = nb0; b1 = nb1;
    }
    __syncthreads();          // all cbuf reads drained; smem reusable as hbuf

    // -------- Phase 3a: ReLU (bias already folded) -> hbuf ------------------
    // C/D: row(image) = q*4 + r, col(neuron) = mn  (verified mapping)
#pragma unroll
    for (int r = 0; r < 4; ++r) {
        int row = q * 4 + r;
        float v;
        v = acc00[r]; v = v > 0.f ? v : 0.f; hbuf[ row       * HSTR + t0 * 16 + mn] = v;
        v = acc01[r]; v = v > 0.f ? v : 0.f; hbuf[ row       * HSTR + t1 * 16 + mn] = v;
        v = acc10[r]; v = v > 0.f ? v : 0.f; hbuf[(row + 16) * HSTR + t0 * 16 + mn] = v;
        v = acc11[r]; v = v > 0.f ? v : 0.f; hbuf[(row + 16) * HSTR + t1 * 16 + mn] = v;
    }
    __syncthreads();

    // -------- Phase 3b: fc2 (fp32 VALU) + store -----------------------------
    for (int p = tid; p < BM * 10; p += 256) {
        int mi = p / 10, o = p - mi * 10;
        const float4* hv = (const float4*)(hbuf + mi * HSTR);
        const float4* w2 = (const float4*)(W2 + (size_t)o * 100);
        float s = b2[o];
#pragma unroll
        for (int g = 0; g < 25; ++g) {
            float4 h4 = hv[g], w4 = w2[g];
            s += h4.x*w4.x + h4.y*w4.y + h4.z*w4.z + h4.w*w4.w;
        }
        out[(size_t)(m0 + mi) * 10 + o] = s;
    }
}

extern "C" void kernel_launch(void* const* d_in, const int* in_sizes, int n_in,
                              void* d_out, int out_size, void* d_ws, size_t ws_size,
                              hipStream_t stream) {
    const float* x  = (const float*)d_in[0];
    const float* cw = (const float*)d_in[1];
    const float* W1 = (const float*)d_in[2];
    const float* b1 = (const float*)d_in[3];
    const float* W2 = (const float*)d_in[4];
    const float* b2 = (const float*)d_in[5];
    float* out = (float*)d_out;
    unsigned short* bw = (unsigned short*)d_ws;    // 180,224 B used

    const int B = in_sizes[0] / 784;               // 65536

    hipLaunchKernelGGL(prep_w1, dim3((NT * KC * 64 + 255) / 256), dim3(256),
                       0, stream, W1, b1, bw);
    hipLaunchKernelGGL(digit_model_fused, dim3(B / BM), dim3(256), 0, stream,
                       x, cw, bw, W2, b2, out);
}